// Round 16
// baseline (1538.764 us; speedup 1.0000x reference)
//
#include <hip/hip_runtime.h>
#include <hip/hip_bf16.h>

typedef __attribute__((ext_vector_type(4))) int int4v;

#define TOKENS 8192
#define IN_F   4096
#define OUT_F  4096

// ws layout (bytes):
//   0     : double hdr[2]  (hdr[0]=mean, hdr[1]=scale)
//   1024  : double partials[1024]
//   9216  : float  xpart[1024]
//   16384 : int8 q[TOKENS][IN_F]
//   16384 + TOKENS*IN_F: int8 s[OUT_F][IN_F]

__global__ __launch_bounds__(256) void k_pre(const float4* __restrict__ w,
                                             const float4* __restrict__ x,
                                             double* __restrict__ partials,
                                             float* __restrict__ xpart) {
  if (blockIdx.x < 1024) {
    __shared__ double sm[256];
    double s = 0.0;
    const float4* p = w + (size_t)blockIdx.x * 4096;
    for (int i = threadIdx.x; i < 4096; i += 256) {
      float4 v = p[i];
      s += (double)v.x + (double)v.y + (double)v.z + (double)v.w;
    }
    sm[threadIdx.x] = s;
    __syncthreads();
    for (int off = 128; off > 0; off >>= 1) {
      if (threadIdx.x < off) sm[threadIdx.x] += sm[threadIdx.x + off];
      __syncthreads();
    }
    if (threadIdx.x == 0) partials[blockIdx.x] = sm[0];
  } else {
    const int b = blockIdx.x - 1024;
    float m = 0.f;
    const size_t n = (size_t)TOKENS * IN_F / 4;
    for (size_t i = (size_t)b * 256 + threadIdx.x; i < n; i += (size_t)1024 * 256) {
      float4 v = x[i];
      m = fmaxf(m, fmaxf(fmaxf(fabsf(v.x), fabsf(v.y)),
                         fmaxf(fabsf(v.z), fabsf(v.w))));
    }
    __shared__ float smf[256];
    smf[threadIdx.x] = m;
    __syncthreads();
    for (int off = 128; off > 0; off >>= 1) {
      if (threadIdx.x < off) smf[threadIdx.x] = fmaxf(smf[threadIdx.x], smf[threadIdx.x + off]);
      __syncthreads();
    }
    if (threadIdx.x == 0) xpart[b] = smf[0];
  }
}

__global__ __launch_bounds__(256) void k_finalize(double* __restrict__ hdr,
                                                  const double* __restrict__ partials,
                                                  const float* __restrict__ xpart) {
  __shared__ double sm[256];
  __shared__ float smf[256];
  double s = partials[threadIdx.x] + partials[threadIdx.x + 256] +
             partials[threadIdx.x + 512] + partials[threadIdx.x + 768];
  float m = fmaxf(fmaxf(xpart[threadIdx.x], xpart[threadIdx.x + 256]),
                  fmaxf(xpart[threadIdx.x + 512], xpart[threadIdx.x + 768]));
  sm[threadIdx.x] = s;
  smf[threadIdx.x] = m;
  __syncthreads();
  for (int off = 128; off > 0; off >>= 1) {
    if (threadIdx.x < off) {
      sm[threadIdx.x] += sm[threadIdx.x + off];
      smf[threadIdx.x] = fmaxf(smf[threadIdx.x], smf[threadIdx.x + off]);
    }
    __syncthreads();
  }
  if (threadIdx.x == 0) {
    hdr[0] = sm[0] / (double)((size_t)OUT_F * IN_F);   // mean of weight
    hdr[1] = 127.0 / (double)smf[0];                   // absmax scale
  }
}

#define QB_BLK ((TOKENS * IN_F / 4) / 256)
#define TB_BLK ((OUT_F * IN_F / 4) / 256)
__global__ __launch_bounds__(256) void k_quant_tern(const float4* __restrict__ x,
                                                    const float4* __restrict__ w,
                                                    int* __restrict__ q,
                                                    int* __restrict__ sgn,
                                                    const double* __restrict__ hdr) {
  if (blockIdx.x < QB_BLK) {
    const double s = hdr[1];
    size_t i = (size_t)blockIdx.x * 256 + threadIdx.x;
    float4 v = x[i];
    int a = (int)rint(s * (double)v.x);
    int b = (int)rint(s * (double)v.y);
    int c = (int)rint(s * (double)v.z);
    int d = (int)rint(s * (double)v.w);
    q[i] = (a & 255) | ((b & 255) << 8) | ((c & 255) << 16) | ((d & 255) << 24);
  } else {
    const double m = hdr[0];
    size_t i = (size_t)(blockIdx.x - QB_BLK) * 256 + threadIdx.x;
    float4 v = w[i];
    int a = ((double)v.x > m) - ((double)v.x < m);
    int b = ((double)v.y > m) - ((double)v.y < m);
    int c = ((double)v.z > m) - ((double)v.z < m);
    int d = ((double)v.w > m) - ((double)v.w < m);
    sgn[i] = (a & 255) | ((b & 255) << 8) | ((c & 255) << 16) | ((d & 255) << 24);
  }
}

// ---------------------------------------------------------------------------
// int8 GEMM, 256x256 tile, BK=64B, ring-2 LDS (64 KB -> TWO blocks/CU),
// 8 waves 2Mx4N, per-wave 128x64. Minimum 2-phase loop (T3-minimum / m97):
//   STAGE(kt+1 -> buf[kt+1&1])  4 gload_lds
//   READ12(buf[kt&1])           12 ds_read_b128
//   lgkm(0); 32 MFMA; vmcnt(0); barrier
// Cross-BLOCK overlap is the lever: two co-resident blocks anti-phase, so
// one block's vmcnt(0)/barrier drain overlaps the other's 1306-cyc MFMA
// cluster (m114 pipe co-scheduling). All prior rounds ran 1 block/CU
// lockstep where drains exposed ~1550 cyc/K-tile regardless of schedule.
// Invariants (full-drain pattern): STAGE(kt+1) overwrites buf[(kt+1)&1],
// whose reads (iter kt-1) were drained by iter kt-1's lgkm(0) and certified
// block-wide by its barrier. READ12(kt) targets buf staged in iter kt-1,
// certified landed by iter kt-1's vmcnt(0)+barrier. Swizzle as R3 (verified
// 0-conflict): stored slot = s ^ ((r>>1)&3), source pre-swizzled (rule #21).
// ---------------------------------------------------------------------------
__global__ __launch_bounds__(512, 4) void k_gemm(const signed char* __restrict__ q,
                                                 const signed char* __restrict__ s,
                                                 float* __restrict__ out) {
  __shared__ signed char sA[2][256 * 64];   // 32 KB
  __shared__ signed char sB[2][256 * 64];   // 32 KB
  const int tid  = threadIdx.x;
  const int lane = tid & 63;
  const int wid  = tid >> 6;     // 0..7
  const int wm   = wid >> 2;     // 0..1 -> row offset wm*128
  const int wn   = wid & 3;      // 0..3 -> col offset wn*64
  const int l15  = lane & 15, l4 = lane >> 4;

  // XCD-aware swizzle: 512 blocks, 8 XCDs, 64 blocks/XCD chunk (bijective)
  const int swz = (blockIdx.x & 7) * 64 + (blockIdx.x >> 3);
  const int bm = swz >> 4;       // 0..31
  const int bn = swz & 15;       // 0..15
  const size_t row0 = (size_t)bm * 256;
  const size_t col0 = (size_t)bn * 256;

  const int lane_off = l15 * 64 + ((l4 ^ ((l15 >> 1) & 3)) << 4);

#define SB0() __builtin_amdgcn_sched_barrier(0)

#define STAGE_AB(KT, BUF)                                                       \
  do {                                                                          \
    const int kt_ = (KT);                                                       \
    _Pragma("unroll")                                                           \
    for (int u = 0; u < 2; ++u) {                                               \
      const int slot = u * 512 + tid;                                           \
      const int r = slot >> 2, sir = slot & 3;                                  \
      const int koff = ((sir ^ ((r >> 1) & 3)) << 4);                           \
      const int ldst = (u * 512 + wid * 64) * 16;                               \
      __builtin_amdgcn_global_load_lds(                                         \
          (const __attribute__((address_space(1))) void*)(q + (row0 + (size_t)r) * IN_F + kt_ * 64 + koff), \
          (__attribute__((address_space(3))) void*)(sA[BUF] + ldst), 16, 0, 0); \
    }                                                                           \
    _Pragma("unroll")                                                           \
    for (int u = 0; u < 2; ++u) {                                               \
      const int slot = u * 512 + tid;                                           \
      const int r = slot >> 2, sir = slot & 3;                                  \
      const int koff = ((sir ^ ((r >> 1) & 3)) << 4);                           \
      const int ldst = (u * 512 + wid * 64) * 16;                               \
      __builtin_amdgcn_global_load_lds(                                         \
          (const __attribute__((address_space(1))) void*)(s + (col0 + (size_t)r) * IN_F + kt_ * 64 + koff), \
          (__attribute__((address_space(3))) void*)(sB[BUF] + ldst), 16, 0, 0); \
    }                                                                           \
  } while (0)

#define READ12(BUF, AV, BV)                                                     \
  do {                                                                          \
    _Pragma("unroll")                                                           \
    for (int f = 0; f < 8; ++f)                                                 \
      AV[f] = *(const int4v*)(sA[BUF] + (wm * 128 + f * 16) * 64 + lane_off);   \
    _Pragma("unroll")                                                           \
    for (int f = 0; f < 4; ++f)                                                 \
      BV[f] = *(const int4v*)(sB[BUF] + (wn * 64 + f * 16) * 64 + lane_off);    \
  } while (0)

#define MFMA32(AV, BV)                                                          \
  do {                                                                          \
    _Pragma("unroll")                                                           \
    for (int m_ = 0; m_ < 8; ++m_)                                              \
      _Pragma("unroll")                                                         \
      for (int n_ = 0; n_ < 4; ++n_)                                            \
        acc[m_][n_] = __builtin_amdgcn_mfma_i32_16x16x64_i8(AV[m_], BV[n_],     \
                                                            acc[m_][n_], 0, 0, 0); \
  } while (0)

#define BODY(KT, CUR, NXT)                                                      \
  do {                                                                          \
    STAGE_AB(((KT) + 1) & 63, NXT);                                             \
    SB0();                                                                      \
    READ12(CUR, av, bv);                                                        \
    asm volatile("s_waitcnt lgkmcnt(0)" ::: "memory");                          \
    SB0();                                                                      \
    __builtin_amdgcn_s_setprio(1);                                              \
    MFMA32(av, bv);                                                             \
    __builtin_amdgcn_s_setprio(0);                                              \
    SB0();                                                                      \
    asm volatile("s_waitcnt vmcnt(0)" ::: "memory");                            \
    SB0();                                                                      \
    __builtin_amdgcn_s_barrier();                                               \
    SB0();                                                                      \
  } while (0)

  int4v acc[8][4];
#pragma unroll
  for (int i = 0; i < 8; ++i)
#pragma unroll
    for (int j = 0; j < 4; ++j) acc[i][j] = int4v{0, 0, 0, 0};

  int4v av[8], bv[4];

  // prologue: stage tile 0 into buf 0; drain; barrier.
  STAGE_AB(0, 0);
  SB0();
  asm volatile("s_waitcnt vmcnt(0)" ::: "memory");
  SB0();
  __builtin_amdgcn_s_barrier();
  SB0();

  for (int kt = 0; kt < 64; kt += 2) {
    BODY(kt + 0, 0, 1);
    BODY(kt + 1, 1, 0);
  }

  // epilogue: C/D mapping col = lane&15, row = (lane>>4)*4 + r
#pragma unroll
  for (int m = 0; m < 8; ++m)
#pragma unroll
    for (int n = 0; n < 4; ++n)
#pragma unroll
      for (int r = 0; r < 4; ++r) {
        const size_t rg = row0 + wm * 128 + m * 16 + l4 * 4 + r;
        const size_t cg = col0 + wn * 64 + n * 16 + l15;
        out[rg * OUT_F + cg] = (float)acc[m][n][r];
      }

#undef SB0
#undef STAGE_AB
#undef READ12
#undef MFMA32
#undef BODY
}

extern "C" void kernel_launch(void* const* d_in, const int* in_sizes, int n_in,
                              void* d_out, int out_size, void* d_ws, size_t ws_size,
                              hipStream_t stream) {
  const float* x = (const float*)d_in[0];   // input  [8192][4096] f32
  const float* w = (const float*)d_in[1];   // weight [4096][4096] f32
  float* out = (float*)d_out;               // [8192][4096] f32

  char* ws = (char*)d_ws;
  double*   hdr      = (double*)ws;
  double*   partials = (double*)(ws + 1024);
  float*    xpart    = (float*)(ws + 9216);
  signed char* qbuf  = (signed char*)(ws + 16384);
  signed char* sbuf  = (signed char*)(ws + 16384 + (size_t)TOKENS * IN_F);

  k_pre<<<2048, 256, 0, stream>>>((const float4*)w, (const float4*)x, partials, xpart);
  k_finalize<<<1, 256, 0, stream>>>(hdr, partials, xpart);
  k_quant_tern<<<QB_BLK + TB_BLK, 256, 0, stream>>>((const float4*)x, (const float4*)w,
                                                    (int*)qbuf, (int*)sbuf, hdr);
  k_gemm<<<(TOKENS / 256) * (OUT_F / 256), 512, 0, stream>>>(qbuf, sbuf, out);
}

// Round 17
// 219.479 us; speedup vs baseline: 7.0110x; 7.0110x over previous
//
#include <hip/hip_runtime.h>
#include <hip/hip_bf16.h>

typedef __attribute__((ext_vector_type(4))) int int4v;

#define TOKENS 8192
#define IN_F   4096
#define OUT_F  4096

// ws layout (bytes):
//   0     : double hdr[2]  (hdr[0]=mean, hdr[1]=scale)
//   1024  : double partials[1024]
//   9216  : float  xpart[1024]
//   16384 : int8 q[TOKENS][IN_F]
//   16384 + TOKENS*IN_F: int8 s[OUT_F][IN_F]

__global__ __launch_bounds__(256) void k_pre(const float4* __restrict__ w,
                                             const float4* __restrict__ x,
                                             double* __restrict__ partials,
                                             float* __restrict__ xpart) {
  if (blockIdx.x < 1024) {
    __shared__ double sm[256];
    double s = 0.0;
    const float4* p = w + (size_t)blockIdx.x * 4096;
    for (int i = threadIdx.x; i < 4096; i += 256) {
      float4 v = p[i];
      s += (double)v.x + (double)v.y + (double)v.z + (double)v.w;
    }
    sm[threadIdx.x] = s;
    __syncthreads();
    for (int off = 128; off > 0; off >>= 1) {
      if (threadIdx.x < off) sm[threadIdx.x] += sm[threadIdx.x + off];
      __syncthreads();
    }
    if (threadIdx.x == 0) partials[blockIdx.x] = sm[0];
  } else {
    const int b = blockIdx.x - 1024;
    float m = 0.f;
    const size_t n = (size_t)TOKENS * IN_F / 4;
    for (size_t i = (size_t)b * 256 + threadIdx.x; i < n; i += (size_t)1024 * 256) {
      float4 v = x[i];
      m = fmaxf(m, fmaxf(fmaxf(fabsf(v.x), fabsf(v.y)),
                         fmaxf(fabsf(v.z), fabsf(v.w))));
    }
    __shared__ float smf[256];
    smf[threadIdx.x] = m;
    __syncthreads();
    for (int off = 128; off > 0; off >>= 1) {
      if (threadIdx.x < off) smf[threadIdx.x] = fmaxf(smf[threadIdx.x], smf[threadIdx.x + off]);
      __syncthreads();
    }
    if (threadIdx.x == 0) xpart[b] = smf[0];
  }
}

__global__ __launch_bounds__(256) void k_finalize(double* __restrict__ hdr,
                                                  const double* __restrict__ partials,
                                                  const float* __restrict__ xpart) {
  __shared__ double sm[256];
  __shared__ float smf[256];
  double s = partials[threadIdx.x] + partials[threadIdx.x + 256] +
             partials[threadIdx.x + 512] + partials[threadIdx.x + 768];
  float m = fmaxf(fmaxf(xpart[threadIdx.x], xpart[threadIdx.x + 256]),
                  fmaxf(xpart[threadIdx.x + 512], xpart[threadIdx.x + 768]));
  sm[threadIdx.x] = s;
  smf[threadIdx.x] = m;
  __syncthreads();
  for (int off = 128; off > 0; off >>= 1) {
    if (threadIdx.x < off) {
      sm[threadIdx.x] += sm[threadIdx.x + off];
      smf[threadIdx.x] = fmaxf(smf[threadIdx.x], smf[threadIdx.x + off]);
    }
    __syncthreads();
  }
  if (threadIdx.x == 0) {
    hdr[0] = sm[0] / (double)((size_t)OUT_F * IN_F);   // mean of weight
    hdr[1] = 127.0 / (double)smf[0];                   // absmax scale
  }
}

#define QB_BLK ((TOKENS * IN_F / 4) / 256)
#define TB_BLK ((OUT_F * IN_F / 4) / 256)
__global__ __launch_bounds__(256) void k_quant_tern(const float4* __restrict__ x,
                                                    const float4* __restrict__ w,
                                                    int* __restrict__ q,
                                                    int* __restrict__ sgn,
                                                    const double* __restrict__ hdr) {
  if (blockIdx.x < QB_BLK) {
    const double s = hdr[1];
    size_t i = (size_t)blockIdx.x * 256 + threadIdx.x;
    float4 v = x[i];
    int a = (int)rint(s * (double)v.x);
    int b = (int)rint(s * (double)v.y);
    int c = (int)rint(s * (double)v.z);
    int d = (int)rint(s * (double)v.w);
    q[i] = (a & 255) | ((b & 255) << 8) | ((c & 255) << 16) | ((d & 255) << 24);
  } else {
    const double m = hdr[0];
    size_t i = (size_t)(blockIdx.x - QB_BLK) * 256 + threadIdx.x;
    float4 v = w[i];
    int a = ((double)v.x > m) - ((double)v.x < m);
    int b = ((double)v.y > m) - ((double)v.y < m);
    int c = ((double)v.z > m) - ((double)v.z < m);
    int d = ((double)v.w > m) - ((double)v.w < m);
    sgn[i] = (a & 255) | ((b & 255) << 8) | ((c & 255) << 16) | ((d & 255) << 24);
  }
}

// ---------------------------------------------------------------------------
// int8 GEMM — exact R3 champion (151.4 us, MfmaUtil 40%, 0 bank conflicts):
// 256x256 tile, BK=64B, 4-deep LDS ring, counted vmcnt(8) never-drain,
// 2 phases/K-tile, XOR-swizzled LDS both-sides (rule #21), XCD swizzle.
// Session evidence (R3-R16): MfmaUtil pinned at 37-40% across 1/2/4/8
// barriers per K-tile, 16x16x64 vs 32x32x32, counted vs full lgkm, 2 vs 4
// waves/SIMD, conflicts or none -> staged-GEMM structure ceiling; this is
// the best measured variant.
// ---------------------------------------------------------------------------
__device__ __forceinline__ void stage2(const signed char* __restrict__ gsrc,
                                       size_t grow0, int ktile,
                                       signed char* ldsbase, int tid, int wid) {
#pragma unroll
  for (int i = 0; i < 2; ++i) {
    const int slot = i * 512 + tid;     // per-lane source slot
    const int r = slot >> 2;            // row 0..255
    const int sir = slot & 3;           // stored 16B position in row
    const signed char* g = gsrc + (grow0 + (size_t)r) * IN_F +
                           (size_t)ktile * 64 + ((sir ^ ((r >> 1) & 3)) << 4);
    __builtin_amdgcn_global_load_lds(
        (const __attribute__((address_space(1))) void*)g,
        (__attribute__((address_space(3))) void*)(ldsbase + (i * 512 + wid * 64) * 16),
        16, 0, 0);
  }
}

__global__ __launch_bounds__(512, 2) void k_gemm(const signed char* __restrict__ q,
                                                 const signed char* __restrict__ s,
                                                 float* __restrict__ out) {
  __shared__ signed char sA[4][256 * 64];   // 64 KB
  __shared__ signed char sB[4][256 * 64];   // 64 KB
  const int tid  = threadIdx.x;
  const int lane = tid & 63;
  const int wid  = tid >> 6;     // 0..7
  const int wm   = wid >> 2;     // 0..1 -> row offset wm*128
  const int wn   = wid & 3;      // 0..3 -> col offset wn*64
  const int l15  = lane & 15, l4 = lane >> 4;

  // XCD-aware swizzle: 512 blocks, 8 XCDs, 64 blocks/XCD chunk (bijective)
  const int swz = (blockIdx.x & 7) * 64 + (blockIdx.x >> 3);
  const int bm = swz >> 4;       // 0..31
  const int bn = swz & 15;       // 0..15
  const size_t row0 = (size_t)bm * 256;
  const size_t col0 = (size_t)bn * 256;

  // per-lane ds_read offset within a 16-row fragment (row = 16-aligned base + l15):
  const int lane_off = l15 * 64 + ((l4 ^ ((l15 >> 1) & 3)) << 4);

  int4v acc[8][4];
#pragma unroll
  for (int i = 0; i < 8; ++i)
#pragma unroll
    for (int j = 0; j < 4; ++j) acc[i][j] = int4v{0, 0, 0, 0};

  // prologue: stage tiles 0,1,2 into bufs 0,1,2
#pragma unroll
  for (int t = 0; t < 3; ++t) {
    stage2(q, row0, t, sA[t], tid, wid);
    stage2(s, col0, t, sB[t], tid, wid);
  }
  asm volatile("s_waitcnt vmcnt(8)" ::: "memory");   // tile 0 landed (own loads)
  __builtin_amdgcn_sched_barrier(0);
  __builtin_amdgcn_s_barrier();
  __builtin_amdgcn_sched_barrier(0);

  for (int kt = 0; kt < 64; ++kt) {
    const int c = kt & 3;
    const int pf   = (kt + 3) & 63;   // wrapped prefetch k-tile (uniform vmcnt)
    const int pbuf = (kt + 3) & 3;
    const signed char* bufA = sA[c];
    const signed char* bufB = sB[c];

    // ---- phase 0: read A(8) + B(0,1), stage A of kt+3, MFMA n={0,1} ----
    int4v a[8], b0, b1;
#pragma unroll
    for (int m = 0; m < 8; ++m)
      a[m] = *(const int4v*)(bufA + (wm * 128 + m * 16) * 64 + lane_off);
    b0 = *(const int4v*)(bufB + (wn * 64 + 0) * 64 + lane_off);
    b1 = *(const int4v*)(bufB + (wn * 64 + 16) * 64 + lane_off);
    stage2(q, row0, pf, sA[pbuf], tid, wid);
    __builtin_amdgcn_sched_barrier(0);
    __builtin_amdgcn_s_barrier();
    asm volatile("s_waitcnt lgkmcnt(0)" ::: "memory");
    __builtin_amdgcn_sched_barrier(0);
    __builtin_amdgcn_s_setprio(1);
#pragma unroll
    for (int m = 0; m < 8; ++m) {
      acc[m][0] = __builtin_amdgcn_mfma_i32_16x16x64_i8(a[m], b0, acc[m][0], 0, 0, 0);
      acc[m][1] = __builtin_amdgcn_mfma_i32_16x16x64_i8(a[m], b1, acc[m][1], 0, 0, 0);
    }
    __builtin_amdgcn_s_setprio(0);
    __builtin_amdgcn_sched_barrier(0);
    __builtin_amdgcn_s_barrier();

    // ---- phase 1: read B(2,3), stage B of kt+3, MFMA n={2,3} ----
    int4v b2 = *(const int4v*)(bufB + (wn * 64 + 32) * 64 + lane_off);
    int4v b3 = *(const int4v*)(bufB + (wn * 64 + 48) * 64 + lane_off);
    stage2(s, col0, pf, sB[pbuf], tid, wid);
    __builtin_amdgcn_sched_barrier(0);
    __builtin_amdgcn_s_barrier();
    asm volatile("s_waitcnt lgkmcnt(0)" ::: "memory");
    __builtin_amdgcn_sched_barrier(0);
    __builtin_amdgcn_s_setprio(1);
#pragma unroll
    for (int m = 0; m < 8; ++m) {
      acc[m][2] = __builtin_amdgcn_mfma_i32_16x16x64_i8(a[m], b2, acc[m][2], 0, 0, 0);
      acc[m][3] = __builtin_amdgcn_mfma_i32_16x16x64_i8(a[m], b3, acc[m][3], 0, 0, 0);
    }
    __builtin_amdgcn_s_setprio(0);
    // end of K-tile: ensure tile kt+1 landed everywhere before next iteration
    asm volatile("s_waitcnt vmcnt(8)" ::: "memory");
    __builtin_amdgcn_sched_barrier(0);
    __builtin_amdgcn_s_barrier();
    __builtin_amdgcn_sched_barrier(0);
  }

  // epilogue: C/D mapping col = lane&15, row = (lane>>4)*4 + r
#pragma unroll
  for (int m = 0; m < 8; ++m)
#pragma unroll
    for (int n = 0; n < 4; ++n)
#pragma unroll
      for (int r = 0; r < 4; ++r) {
        const size_t rg = row0 + wm * 128 + m * 16 + l4 * 4 + r;
        const size_t cg = col0 + wn * 64 + n * 16 + l15;
        out[rg * OUT_F + cg] = (float)acc[m][n][r];
      }
}

extern "C" void kernel_launch(void* const* d_in, const int* in_sizes, int n_in,
                              void* d_out, int out_size, void* d_ws, size_t ws_size,
                              hipStream_t stream) {
  const float* x = (const float*)d_in[0];   // input  [8192][4096] f32
  const float* w = (const float*)d_in[1];   // weight [4096][4096] f32
  float* out = (float*)d_out;               // [8192][4096] f32

  char* ws = (char*)d_ws;
  double*   hdr      = (double*)ws;
  double*   partials = (double*)(ws + 1024);
  float*    xpart    = (float*)(ws + 9216);
  signed char* qbuf  = (signed char*)(ws + 16384);
  signed char* sbuf  = (signed char*)(ws + 16384 + (size_t)TOKENS * IN_F);

  k_pre<<<2048, 256, 0, stream>>>((const float4*)w, (const float4*)x, partials, xpart);
  k_finalize<<<1, 256, 0, stream>>>(hdr, partials, xpart);
  k_quant_tern<<<QB_BLK + TB_BLK, 256, 0, stream>>>((const float4*)x, (const float4*)w,
                                                    (int*)qbuf, (int*)sbuf, hdr);
  k_gemm<<<(TOKENS / 256) * (OUT_F / 256), 512, 0, stream>>>(qbuf, sbuf, out);
}

// Round 18
// 219.364 us; speedup vs baseline: 7.0146x; 1.0005x over previous
//
#include <hip/hip_runtime.h>
#include <hip/hip_bf16.h>

typedef __attribute__((ext_vector_type(4))) int int4v;

#define TOKENS 8192
#define IN_F   4096
#define OUT_F  4096

// ws layout (bytes):
//   0     : double hdr[2]  (hdr[0]=mean, hdr[1]=scale)
//   1024  : double partials[1024]
//   9216  : float  xpart[1024]
//   16384 : int8 q[TOKENS][IN_F]
//   16384 + TOKENS*IN_F: int8 s[OUT_F][IN_F]

__global__ __launch_bounds__(256) void k_pre(const float4* __restrict__ w,
                                             const float4* __restrict__ x,
                                             double* __restrict__ partials,
                                             float* __restrict__ xpart) {
  if (blockIdx.x < 1024) {
    __shared__ double sm[256];
    double s = 0.0;
    const float4* p = w + (size_t)blockIdx.x * 4096;
    for (int i = threadIdx.x; i < 4096; i += 256) {
      float4 v = p[i];
      s += (double)v.x + (double)v.y + (double)v.z + (double)v.w;
    }
    sm[threadIdx.x] = s;
    __syncthreads();
    for (int off = 128; off > 0; off >>= 1) {
      if (threadIdx.x < off) sm[threadIdx.x] += sm[threadIdx.x + off];
      __syncthreads();
    }
    if (threadIdx.x == 0) partials[blockIdx.x] = sm[0];
  } else {
    const int b = blockIdx.x - 1024;
    float m = 0.f;
    const size_t n = (size_t)TOKENS * IN_F / 4;
    for (size_t i = (size_t)b * 256 + threadIdx.x; i < n; i += (size_t)1024 * 256) {
      float4 v = x[i];
      m = fmaxf(m, fmaxf(fmaxf(fabsf(v.x), fabsf(v.y)),
                         fmaxf(fabsf(v.z), fabsf(v.w))));
    }
    __shared__ float smf[256];
    smf[threadIdx.x] = m;
    __syncthreads();
    for (int off = 128; off > 0; off >>= 1) {
      if (threadIdx.x < off) smf[threadIdx.x] = fmaxf(smf[threadIdx.x], smf[threadIdx.x + off]);
      __syncthreads();
    }
    if (threadIdx.x == 0) xpart[b] = smf[0];
  }
}

__global__ __launch_bounds__(256) void k_finalize(double* __restrict__ hdr,
                                                  const double* __restrict__ partials,
                                                  const float* __restrict__ xpart) {
  __shared__ double sm[256];
  __shared__ float smf[256];
  double s = partials[threadIdx.x] + partials[threadIdx.x + 256] +
             partials[threadIdx.x + 512] + partials[threadIdx.x + 768];
  float m = fmaxf(fmaxf(xpart[threadIdx.x], xpart[threadIdx.x + 256]),
                  fmaxf(xpart[threadIdx.x + 512], xpart[threadIdx.x + 768]));
  sm[threadIdx.x] = s;
  smf[threadIdx.x] = m;
  __syncthreads();
  for (int off = 128; off > 0; off >>= 1) {
    if (threadIdx.x < off) {
      sm[threadIdx.x] += sm[threadIdx.x + off];
      smf[threadIdx.x] = fmaxf(smf[threadIdx.x], smf[threadIdx.x + off]);
    }
    __syncthreads();
  }
  if (threadIdx.x == 0) {
    hdr[0] = sm[0] / (double)((size_t)OUT_F * IN_F);   // mean of weight
    hdr[1] = 127.0 / (double)smf[0];                   // absmax scale
  }
}

#define QB_BLK ((TOKENS * IN_F / 4) / 256)
#define TB_BLK ((OUT_F * IN_F / 4) / 256)
__global__ __launch_bounds__(256) void k_quant_tern(const float4* __restrict__ x,
                                                    const float4* __restrict__ w,
                                                    int* __restrict__ q,
                                                    int* __restrict__ sgn,
                                                    const double* __restrict__ hdr) {
  if (blockIdx.x < QB_BLK) {
    const double s = hdr[1];
    size_t i = (size_t)blockIdx.x * 256 + threadIdx.x;
    float4 v = x[i];
    int a = (int)rint(s * (double)v.x);
    int b = (int)rint(s * (double)v.y);
    int c = (int)rint(s * (double)v.z);
    int d = (int)rint(s * (double)v.w);
    q[i] = (a & 255) | ((b & 255) << 8) | ((c & 255) << 16) | ((d & 255) << 24);
  } else {
    const double m = hdr[0];
    size_t i = (size_t)(blockIdx.x - QB_BLK) * 256 + threadIdx.x;
    float4 v = w[i];
    int a = ((double)v.x > m) - ((double)v.x < m);
    int b = ((double)v.y > m) - ((double)v.y < m);
    int c = ((double)v.z > m) - ((double)v.z < m);
    int d = ((double)v.w > m) - ((double)v.w < m);
    sgn[i] = (a & 255) | ((b & 255) << 8) | ((c & 255) << 16) | ((d & 255) << 24);
  }
}

// ---------------------------------------------------------------------------
// int8 GEMM — R3/R17 champion skeleton (256x256 tile, BK=64B, ring-4 LDS,
// 2 phases/K-tile, counted vmcnt(8) never-drain, XOR swizzle both-sides,
// XCD swizzle) with hand lgkmcnt(0) + sched_barrier(0) pins REMOVED inside
// phases. Rationale (m141 + m97 asm evidence): the compiler emits a
// descending fine-grained lgkmcnt ladder so the first MFMA starts once its
// own operands land and the remaining ds_reads drain UNDER the MFMA cluster;
// the hand lgkm(0)+sched_barrier(0) in R3/R17 serialized the full 10-read
// latency in front of every 16-MFMA cluster. Kept fences: the counted
// vmcnt(8) asm ("memory" clobber) + raw s_barrier pairs that certify ring
// buffer lifetimes (compiler cannot derive those). ds_reads are plain C
// loads (compiler-visible deps; rule #18's inline-asm hazard doesn't apply).
// Ring invariants identical to R3: stage(kt+3) overwrites buf[(kt-1)&3]
// whose reads finished an iteration ago (certified by the end-of-K-tile
// barrier); reads of tile kt+1 follow the vmcnt(8)+barrier that certified
// its 4 stage-loads (oldest of 12 outstanding) landed.
// ---------------------------------------------------------------------------
__device__ __forceinline__ void stage2(const signed char* __restrict__ gsrc,
                                       size_t grow0, int ktile,
                                       signed char* ldsbase, int tid, int wid) {
#pragma unroll
  for (int i = 0; i < 2; ++i) {
    const int slot = i * 512 + tid;     // per-lane source slot
    const int r = slot >> 2;            // row 0..255
    const int sir = slot & 3;           // stored 16B position in row
    const signed char* g = gsrc + (grow0 + (size_t)r) * IN_F +
                           (size_t)ktile * 64 + ((sir ^ ((r >> 1) & 3)) << 4);
    __builtin_amdgcn_global_load_lds(
        (const __attribute__((address_space(1))) void*)g,
        (__attribute__((address_space(3))) void*)(ldsbase + (i * 512 + wid * 64) * 16),
        16, 0, 0);
  }
}

__global__ __launch_bounds__(512, 2) void k_gemm(const signed char* __restrict__ q,
                                                 const signed char* __restrict__ s,
                                                 float* __restrict__ out) {
  __shared__ signed char sA[4][256 * 64];   // 64 KB
  __shared__ signed char sB[4][256 * 64];   // 64 KB
  const int tid  = threadIdx.x;
  const int lane = tid & 63;
  const int wid  = tid >> 6;     // 0..7
  const int wm   = wid >> 2;     // 0..1 -> row offset wm*128
  const int wn   = wid & 3;      // 0..3 -> col offset wn*64
  const int l15  = lane & 15, l4 = lane >> 4;

  // XCD-aware swizzle: 512 blocks, 8 XCDs, 64 blocks/XCD chunk (bijective)
  const int swz = (blockIdx.x & 7) * 64 + (blockIdx.x >> 3);
  const int bm = swz >> 4;       // 0..31
  const int bn = swz & 15;       // 0..15
  const size_t row0 = (size_t)bm * 256;
  const size_t col0 = (size_t)bn * 256;

  // per-lane ds_read offset within a 16-row fragment (row = 16-aligned base + l15):
  const int lane_off = l15 * 64 + ((l4 ^ ((l15 >> 1) & 3)) << 4);

  int4v acc[8][4];
#pragma unroll
  for (int i = 0; i < 8; ++i)
#pragma unroll
    for (int j = 0; j < 4; ++j) acc[i][j] = int4v{0, 0, 0, 0};

  // prologue: stage tiles 0,1,2 into bufs 0,1,2
#pragma unroll
  for (int t = 0; t < 3; ++t) {
    stage2(q, row0, t, sA[t], tid, wid);
    stage2(s, col0, t, sB[t], tid, wid);
  }
  asm volatile("s_waitcnt vmcnt(8)" ::: "memory");   // tile 0 landed (own loads)
  __builtin_amdgcn_s_barrier();

  for (int kt = 0; kt < 64; ++kt) {
    const int c = kt & 3;
    const int pf   = (kt + 3) & 63;   // wrapped prefetch k-tile (uniform vmcnt)
    const int pbuf = (kt + 3) & 3;
    const signed char* bufA = sA[c];
    const signed char* bufB = sB[c];

    // ---- phase 0: read A(8) + B(0,1), stage A of kt+3, MFMA n={0,1} ----
    // No hand lgkm / sched_barrier: compiler emits the descending lgkmcnt
    // ladder so MFMAs start as soon as their own operands land.
    int4v a[8], b0, b1;
#pragma unroll
    for (int m = 0; m < 8; ++m)
      a[m] = *(const int4v*)(bufA + (wm * 128 + m * 16) * 64 + lane_off);
    b0 = *(const int4v*)(bufB + (wn * 64 + 0) * 64 + lane_off);
    b1 = *(const int4v*)(bufB + (wn * 64 + 16) * 64 + lane_off);
    stage2(q, row0, pf, sA[pbuf], tid, wid);
    __builtin_amdgcn_s_barrier();
    __builtin_amdgcn_s_setprio(1);
#pragma unroll
    for (int m = 0; m < 8; ++m) {
      acc[m][0] = __builtin_amdgcn_mfma_i32_16x16x64_i8(a[m], b0, acc[m][0], 0, 0, 0);
      acc[m][1] = __builtin_amdgcn_mfma_i32_16x16x64_i8(a[m], b1, acc[m][1], 0, 0, 0);
    }
    __builtin_amdgcn_s_setprio(0);
    __builtin_amdgcn_s_barrier();

    // ---- phase 1: read B(2,3), stage B of kt+3, MFMA n={2,3} ----
    int4v b2 = *(const int4v*)(bufB + (wn * 64 + 32) * 64 + lane_off);
    int4v b3 = *(const int4v*)(bufB + (wn * 64 + 48) * 64 + lane_off);
    stage2(s, col0, pf, sB[pbuf], tid, wid);
    __builtin_amdgcn_s_barrier();
    __builtin_amdgcn_s_setprio(1);
#pragma unroll
    for (int m = 0; m < 8; ++m) {
      acc[m][2] = __builtin_amdgcn_mfma_i32_16x16x64_i8(a[m], b2, acc[m][2], 0, 0, 0);
      acc[m][3] = __builtin_amdgcn_mfma_i32_16x16x64_i8(a[m], b3, acc[m][3], 0, 0, 0);
    }
    __builtin_amdgcn_s_setprio(0);
    // end of K-tile: tile kt+1 landed everywhere before next iteration
    asm volatile("s_waitcnt vmcnt(8)" ::: "memory");
    __builtin_amdgcn_s_barrier();
  }

  // epilogue: C/D mapping col = lane&15, row = (lane>>4)*4 + r
#pragma unroll
  for (int m = 0; m < 8; ++m)
#pragma unroll
    for (int n = 0; n < 4; ++n)
#pragma unroll
      for (int r = 0; r < 4; ++r) {
        const size_t rg = row0 + wm * 128 + m * 16 + l4 * 4 + r;
        const size_t cg = col0 + wn * 64 + n * 16 + l15;
        out[rg * OUT_F + cg] = (float)acc[m][n][r];
      }
}

extern "C" void kernel_launch(void* const* d_in, const int* in_sizes, int n_in,
                              void* d_out, int out_size, void* d_ws, size_t ws_size,
                              hipStream_t stream) {
  const float* x = (const float*)d_in[0];   // input  [8192][4096] f32
  const float* w = (const float*)d_in[1];   // weight [4096][4096] f32
  float* out = (float*)d_out;               // [8192][4096] f32

  char* ws = (char*)d_ws;
  double*   hdr      = (double*)ws;
  double*   partials = (double*)(ws + 1024);
  float*    xpart    = (float*)(ws + 9216);
  signed char* qbuf  = (signed char*)(ws + 16384);
  signed char* sbuf  = (signed char*)(ws + 16384 + (size_t)TOKENS * IN_F);

  k_pre<<<2048, 256, 0, stream>>>((const float4*)w, (const float4*)x, partials, xpart);
  k_finalize<<<1, 256, 0, stream>>>(hdr, partials, xpart);
  k_quant_tern<<<QB_BLK + TB_BLK, 256, 0, stream>>>((const float4*)x, (const float4*)w,
                                                    (int*)qbuf, (int*)sbuf, hdr);
  k_gemm<<<(TOKENS / 256) * (OUT_F / 256), 512, 0, stream>>>(qbuf, sbuf, out);
}